// Round 14
// baseline (101.792 us; speedup 1.0000x reference)
//
#include <hip/hip_runtime.h>
#include <stdint.h>

#define T_TOK 4096
#define KTOP  2
#define HS    512
#define FFN   2048
#define NE    8
#define NA    (T_TOK*KTOP)     // 8192 assignments
#define MT    128              // M-tile
#define BK    64               // K-step
#define MT_MAX 72              // 8 XCD chunks x 9
#define SLOT_CAP (MT_MAX*MT)   // 9216
#define PSTR 68                // epilogue LDS f32 stride
#define NB_G1 576              // gemm1 blocks (128x256 tiles) in fused launch

// ---------------- workspace layout (bytes) ----------------
#define MB_ (1024ull*1024ull)
#define WS_OFF   1024u         // 9 ints
#define WS_MEXP  1088u         // 72 ints
#define WS_SLOTS 2048u         // 9216 ints
#define WS_INV   40960u        // 8192 ints
#define WS_XB   (1*MB_)        // 4MB  bf16 [4096][512]
#define WS_W1T  (5*MB_)        // 16MB bf16 [8][2048][512]
#define WS_W2T  (21*MB_)       // 16MB bf16 [8][512][2048]
#define WS_HB   (37*MB_)       // 36MB bf16 [9216][2048]
#define WS_YPB0 (73*MB_)       // 9MB bf16 [9216][512]
#define WS_YPB1 (82*MB_)       // 9MB
#define WS_NEED (91*MB_)

typedef short bf16x8 __attribute__((ext_vector_type(8)));
typedef float f32x4  __attribute__((ext_vector_type(4)));

__device__ __forceinline__ unsigned short f2bf(float f) {
    unsigned u = __builtin_bit_cast(unsigned, f);
    u += 0x7fffu + ((u >> 16) & 1u);          // RNE
    return (unsigned short)(u >> 16);
}
__device__ __forceinline__ float bf2f(unsigned short h) {
    return __builtin_bit_cast(float, (unsigned)h << 16);
}
// tanh-approx gelu (~10 VALU ops vs erff ~30; |err| <= ~3e-3; inf-safe both tails)
__device__ __forceinline__ float gelu_fast(float x) {
    float x2 = x * x;
    float inner = fmaf(0.044715f * x2, x, x);
    float E = __expf(1.5957691216057308f * inner);
    return x - x / (1.0f + E);
}
__device__ __forceinline__ void gl_lds16(const void* g, void* l) {
    __builtin_amdgcn_global_load_lds(
        (const __attribute__((address_space(1))) unsigned int*)g,
        (__attribute__((address_space(3))) unsigned int*)l, 16, 0, 0);
}

// 64x64 transpose+cvt tile: float4 global reads (1KB/inst), ushort4 writes.
__device__ __forceinline__ void transpose_cvt64(
    const float* __restrict__ src, unsigned short* __restrict__ dh,
    int R, int C, int e, int kb, int nb, int t, float (*tile)[65])
{
    const int k0 = kb * 64, n0 = nb * 64;
    #pragma unroll
    for (int q = 0; q < 4; ++q) {
        int f4 = t + q * 256;
        int kk = f4 >> 4, nn4 = f4 & 15;
        float4 v = *reinterpret_cast<const float4*>(
            &src[((size_t)e * R + k0 + kk) * C + n0 + nn4 * 4]);
        tile[kk][nn4 * 4 + 0] = v.x; tile[kk][nn4 * 4 + 1] = v.y;
        tile[kk][nn4 * 4 + 2] = v.z; tile[kk][nn4 * 4 + 3] = v.w;
    }
    __syncthreads();
    #pragma unroll
    for (int q = 0; q < 4; ++q) {
        int wid = t + q * 256;
        int nn = wid >> 4, kk4 = wid & 15;
        ushort4 o;
        o.x = f2bf(tile[kk4 * 4 + 0][nn]);
        o.y = f2bf(tile[kk4 * 4 + 1][nn]);
        o.z = f2bf(tile[kk4 * 4 + 2][nn]);
        o.w = f2bf(tile[kk4 * 4 + 3][nn]);
        *reinterpret_cast<ushort4*>(&dh[((size_t)e * C + n0 + nn) * R + k0 + kk4 * 4]) = o;
    }
}

// ---------------- prep1: cvt_x + w1T + deterministic routing ----------------
// ranges: [0,2048) x->bf16 | [2048,4096) w1T | [4096,4129) routing.
// Every range writes disjoint data consumed only by LATER kernels (R5 lesson).
__global__ void moe_prep1(const int* __restrict__ eidx,
                          int* slots, int* inv, int* offp, int* mexp,
                          const float* __restrict__ x, unsigned short* __restrict__ xb,
                          const float* __restrict__ w1, unsigned short* __restrict__ w1t)
{
    __shared__ float tile[64][65];
    const int bid = blockIdx.x, t = threadIdx.x;
    if (bid < 2048) {                         // x -> bf16
        int i = bid * 256 + t;
        float4 v = reinterpret_cast<const float4*>(x)[i];
        uint2 p = { (unsigned)f2bf(v.x) | ((unsigned)f2bf(v.y) << 16),
                    (unsigned)f2bf(v.z) | ((unsigned)f2bf(v.w) << 16) };
        reinterpret_cast<uint2*>(xb)[i] = p;
    } else if (bid < 4096) {                  // w1 [e][HS][FFN] -> [e][FFN][HS]
        int lin = bid - 2048, e = lin >> 8, rem = lin & 255;
        transpose_cvt64(w1, w1t, HS, FFN, e, rem & 7, rem >> 3, t, tile);
    } else {                                  // deterministic routing
        __shared__ int hfull[NE], hpre[NE], elocal[256];
        __shared__ int off_l[NE + 1];
        const int f = bid - 4096;             // 0..32
        if (t < NE) { hfull[t] = 0; hpre[t] = 0; }
        __syncthreads();
        const int base = f * 256;             // f==32 -> base==NA (no local slice)
        for (int i = t; i < NA; i += 256) {
            int ee = eidx[i];
            atomicAdd(&hfull[ee], 1);         // LDS atomics: cheap
            if (i < base) atomicAdd(&hpre[ee], 1);
        }
        if (f < 32) elocal[t] = eidx[base + t];
        __syncthreads();
        if (t == 0) {
            int run = 0;
            for (int q = 0; q < NE; ++q) { off_l[q] = run; run += ((hfull[q] + MT - 1) / MT) * MT; }
            off_l[NE] = run;
        }
        __syncthreads();
        if (f < 32) {
            int a = base + t, e = elocal[t];
            int rank = 0;
            for (int j = 0; j < t; ++j) rank += (elocal[j] == e) ? 1 : 0;
            int s = off_l[e] + hpre[e] + rank;
            slots[s] = a;                     // deterministic (stable order)
            inv[a] = s;
        } else {
            for (int e = 0; e < NE; ++e)
                for (int s = off_l[e] + hfull[e] + t; s < off_l[e + 1]; s += 256)
                    slots[s] = -1;            // pads (poison-safe each call)
            for (int s = off_l[NE] + t; s < SLOT_CAP; s += 256) slots[s] = -1;
            if (t <= NE) offp[t] = off_l[t];
            if (t < MT_MAX) {                 // mexp[t]: expert owning tile t
                int m0 = t * MT, ee = 0;
                #pragma unroll
                for (int q = 0; q < NE; ++q)
                    if (m0 >= off_l[q] && m0 < off_l[q + 1]) ee = q;
                mexp[t] = ee;
            }
        }
    }
}

// ---------------- fused: gemm1 128x256 (bid<576) + w2T transpose (bid>=576) ----------------
// gemm1: 64 MFMA per barrier-pair (2x the 128x128 tile) -> barrier-stall share
// halves (R13: MfmaUtil 16%, all pipes low -> barrier/latency bound).
// LDS: As 16KB + Bs 32KB staging; Pf 34.8KB epilogue overlay; ~2-3 blocks/CU.
__global__ __launch_bounds__(256, 2) void moe_g1w2(
    const unsigned short* __restrict__ XB, const unsigned short* __restrict__ W1T,
    const int* __restrict__ offp, const int* __restrict__ mexp,
    const int* __restrict__ slots, unsigned short* __restrict__ HB,
    const float* __restrict__ w2, unsigned short* __restrict__ w2t)
{
    __shared__ __align__(16) char POOL[49152];   // 48KB staging U 34.8KB epilogue
    __shared__ int srow[MT];
    const int t = threadIdx.x;

    if (blockIdx.x >= NB_G1) {                // ---- w2T path ----
        int lin = blockIdx.x - NB_G1;         // 0..2047
        int e = lin >> 8, rem = lin & 255;
        transpose_cvt64(w2, w2t, FFN, HS, e, rem & 31, rem >> 5, t,
                        reinterpret_cast<float(*)[65]>(POOL));
        return;
    }

    // ---- gemm1 path: 128 rows x 256 cols per block ----
    const int xcd = blockIdx.x & 7;
    const int part = blockIdx.x >> 3;     // 0..71
    const int mtg = part % 9;
    const int nt  = part / 9;             // 0..7 (256-wide panels)
    const int mt  = xcd * 9 + mtg;
    if (mt * MT >= offp[NE]) return;
    const int e = mexp[mt];
    const int lane = t & 63, wv = t >> 6;

    short* As = (short*)POOL;                 // 16KB [128][64] bf16, 8-group XOR swz
    short* Bs = (short*)(POOL + 16384);       // 32KB [256][64] bf16
    float* Pf = (float*)POOL;                 // epilogue overlay [128][PSTR]

    if (t < MT) { int s = slots[mt * MT + t]; srow[t] = (s < 0) ? 0 : (s >> 1); }
    __syncthreads();

    // staging: A 4 insts/wave (rows i*8..), B 8 insts/wave (rows j*8..)
    int baseA[4], baseB[8];
    #pragma unroll
    for (int q = 0; q < 4; ++q) {
        int i = wv * 4 + q;
        int row = i * 8 + (lane >> 3);
        int sg = (lane & 7) ^ (row & 7);      // source swz [rule 21: both sides]
        baseA[q] = srow[row] * HS + sg * 8;
    }
    #pragma unroll
    for (int q = 0; q < 8; ++q) {
        int j = wv * 8 + q;
        int row = j * 8 + (lane >> 3);        // 0..255 within 256-panel
        int sg = (lane & 7) ^ (row & 7);
        baseB[q] = (e * FFN + nt * 256 + row) * HS + sg * 8;
    }

    const int wm = wv >> 1, wn = wv & 1, q4 = lane >> 4, l15 = lane & 15;
    int offA[2][4], offB[2][8];
    #pragma unroll
    for (int m = 0; m < 4; ++m) {
        int r = wm * 64 + m * 16 + l15;
        #pragma unroll
        for (int ks = 0; ks < 2; ++ks)
            offA[ks][m] = r * 128 + ((((ks << 2) | q4) ^ (r & 7)) << 4);
    }
    #pragma unroll
    for (int n = 0; n < 8; ++n) {
        int rb = wn * 128 + n * 16 + l15;     // 0..255
        #pragma unroll
        for (int ks = 0; ks < 2; ++ks)
            offB[ks][n] = rb * 128 + ((((ks << 2) | q4) ^ (rb & 7)) << 4);
    }

    f32x4 acc[4][8];
    #pragma unroll
    for (int m = 0; m < 4; ++m)
        #pragma unroll
        for (int n = 0; n < 8; ++n) { f32x4 z = {0.f, 0.f, 0.f, 0.f}; acc[m][n] = z; }

    for (int kk = 0; kk < HS; kk += BK) {
        __syncthreads();
        #pragma unroll
        for (int q = 0; q < 4; ++q)
            gl_lds16(XB + baseA[q] + kk, (char*)As + (wv * 4 + q) * 1024);
        #pragma unroll
        for (int q = 0; q < 8; ++q)
            gl_lds16(W1T + baseB[q] + kk, (char*)Bs + (wv * 8 + q) * 1024);
        __syncthreads();
        #pragma unroll
        for (int ks = 0; ks < 2; ++ks) {
            bf16x8 a[4], b[8];
            #pragma unroll
            for (int m = 0; m < 4; ++m)
                a[m] = *(const bf16x8*)((const char*)As + offA[ks][m]);
            #pragma unroll
            for (int n = 0; n < 8; ++n)
                b[n] = *(const bf16x8*)((const char*)Bs + offB[ks][n]);
            #pragma unroll
            for (int m = 0; m < 4; ++m)
                #pragma unroll
                for (int n = 0; n < 8; ++n)
                    acc[m][n] = __builtin_amdgcn_mfma_f32_16x16x32_bf16(a[m], b[n], acc[m][n], 0, 0, 0);
        }
    }

    // epilogue: 4 column-quarters of 64 via Pf[128][PSTR] (fast gelu on read)
    #pragma unroll
    for (int qq = 0; qq < 4; ++qq) {
        const int wn_q = qq >> 1, nq = (qq & 1) * 4;
        __syncthreads();
        if (wn == wn_q) {
            #pragma unroll
            for (int m = 0; m < 4; ++m)
                #pragma unroll
                for (int nn = 0; nn < 4; ++nn)
                    #pragma unroll
                    for (int j = 0; j < 4; ++j)
                        Pf[(wm * 64 + m * 16 + q4 * 4 + j) * PSTR + nn * 16 + l15] = acc[m][nq + nn][j];
        }
        __syncthreads();
        #pragma unroll
        for (int q = 0; q < 4; ++q) {
            int seg = q * 256 + t, row = seg >> 3, c8 = (seg & 7) << 3;
            const float* p = Pf + row * PSTR + c8;
            float4 a = *(const float4*)p, b = *(const float4*)(p + 4);
            float va[8] = {a.x, a.y, a.z, a.w, b.x, b.y, b.z, b.w};
            bf16x8 ph;
            #pragma unroll
            for (int i = 0; i < 8; ++i) ph[i] = (short)f2bf(gelu_fast(va[i]));
            *(bf16x8*)(HB + (size_t)(mt * MT + row) * FFN + nt * 256 + qq * 64 + c8) = ph;
        }
    }
}

// ---------------- grouped GEMM2: Y = H @ W2, split-K=2, bf16 partials ----------------
// Grid 576. sub-FAST decode: the 8 concurrent blocks on one XCD are all (nt,kpart)
// jobs of ONE mt -> A panel fetched once; B survives L2 across mtg rounds.
__global__ __launch_bounds__(256, 4) void moe_gemm2(
    const unsigned short* __restrict__ HB, const unsigned short* __restrict__ W2T,
    const int* __restrict__ offp, const int* __restrict__ mexp,
    unsigned short* __restrict__ YPB0, unsigned short* __restrict__ YPB1)
{
    const int xcd = blockIdx.x & 7;
    const int part = blockIdx.x >> 3;     // 0..71
    const int sub = part % 8;             // FAST: share one mt's A panel
    const int mtg = part / 8;             // 0..8
    const int mt  = xcd * 9 + mtg;
    const int nt  = sub >> 1, kpart = sub & 1;
    if (mt * MT >= offp[NE]) return;
    const int e = mexp[mt];
    const int t = threadIdx.x, lane = t & 63, wv = t >> 6;

    __shared__ __align__(16) char POOL[MT * PSTR * 4];
    short* As = (short*)POOL;
    short* Bs = (short*)(POOL + 16384);
    float* Pf = (float*)POOL;

    int baseA[4], baseB[4];
    #pragma unroll
    for (int q = 0; q < 4; ++q) {
        int i = wv * 4 + q;
        int row = i * 8 + (lane >> 3);
        int sg = (lane & 7) ^ (row & 7);
        baseA[q] = (mt * MT + row) * FFN + sg * 8;
        baseB[q] = (e * HS + nt * MT + row) * FFN + sg * 8;
    }

    const int wm = wv >> 1, wn = wv & 1, q4 = lane >> 4, l15 = lane & 15;
    int offA[2][4], offB[2][4];
    #pragma unroll
    for (int m = 0; m < 4; ++m) {
        int r  = wm * 64 + m * 16 + l15;
        int rb = wn * 64 + m * 16 + l15;
        #pragma unroll
        for (int ks = 0; ks < 2; ++ks) {
            offA[ks][m] = r  * 128 + ((((ks << 2) | q4) ^ (r  & 7)) << 4);
            offB[ks][m] = rb * 128 + ((((ks << 2) | q4) ^ (rb & 7)) << 4);
        }
    }

    f32x4 acc[4][4];
    #pragma unroll
    for (int m = 0; m < 4; ++m)
        #pragma unroll
        for (int n = 0; n < 4; ++n) { f32x4 z = {0.f, 0.f, 0.f, 0.f}; acc[m][n] = z; }

    const int k0 = kpart * (FFN / 2), k1 = k0 + FFN / 2;
    for (int kk = k0; kk < k1; kk += BK) {
        __syncthreads();
        #pragma unroll
        for (int q = 0; q < 4; ++q) {
            int i = wv * 4 + q;
            gl_lds16(HB  + baseA[q] + kk, (char*)As + i * 1024);
            gl_lds16(W2T + baseB[q] + kk, (char*)Bs + i * 1024);
        }
        __syncthreads();
        #pragma unroll
        for (int ks = 0; ks < 2; ++ks) {
            bf16x8 a[4], b[4];
            #pragma unroll
            for (int m = 0; m < 4; ++m) {
                a[m] = *(const bf16x8*)((const char*)As + offA[ks][m]);
                b[m] = *(const bf16x8*)((const char*)Bs + offB[ks][m]);
            }
            #pragma unroll
            for (int m = 0; m < 4; ++m)
                #pragma unroll
                for (int n = 0; n < 4; ++n)
                    acc[m][n] = __builtin_amdgcn_mfma_f32_16x16x32_bf16(a[m], b[n], acc[m][n], 0, 0, 0);
        }
    }

    unsigned short* YP = kpart ? YPB1 : YPB0;
    #pragma unroll
    for (int half = 0; half < 2; ++half) {
        __syncthreads();
        if (wn == half) {
            #pragma unroll
            for (int m = 0; m < 4; ++m)
                #pragma unroll
                for (int n = 0; n < 4; ++n)
                    #pragma unroll
                    for (int j = 0; j < 4; ++j)
                        Pf[(wm * 64 + m * 16 + q4 * 4 + j) * PSTR + n * 16 + l15] = acc[m][n][j];
        }
        __syncthreads();
        #pragma unroll
        for (int q = 0; q < 4; ++q) {
            int seg = q * 256 + t, row = seg >> 3, c8 = (seg & 7) << 3;
            const float* p = Pf + row * PSTR + c8;
            float4 a = *(const float4*)p, b = *(const float4*)(p + 4);
            float va[8] = {a.x, a.y, a.z, a.w, b.x, b.y, b.z, b.w};
            bf16x8 ph;
            #pragma unroll
            for (int i = 0; i < 8; ++i) ph[i] = (short)f2bf(va[i]);
            *(bf16x8*)(YP + (size_t)(mt * MT + row) * HS + nt * MT + half * 64 + c8) = ph;
        }
    }
}

// ---------------- combine (bf16 partials) ----------------
__global__ void moe_combine2(const unsigned short* __restrict__ YPB0,
                             const unsigned short* __restrict__ YPB1,
                             const int* __restrict__ inv, const float* __restrict__ ew,
                             float* __restrict__ out) {
    int i = blockIdx.x * 256 + threadIdx.x;      // over T*HS/8 groups of 8
    if (i >= T_TOK * HS / 8) return;
    int tk = i >> 6, c8 = (i & 63) << 3;
    int s0 = inv[2 * tk], s1 = inv[2 * tk + 1];
    float w0 = ew[2 * tk], w1 = ew[2 * tk + 1];
    bf16x8 a0 = *(const bf16x8*)(YPB0 + (size_t)s0 * HS + c8);
    bf16x8 b0 = *(const bf16x8*)(YPB1 + (size_t)s0 * HS + c8);
    bf16x8 a1 = *(const bf16x8*)(YPB0 + (size_t)s1 * HS + c8);
    bf16x8 b1 = *(const bf16x8*)(YPB1 + (size_t)s1 * HS + c8);
    float o[8];
    #pragma unroll
    for (int j = 0; j < 8; ++j)
        o[j] = w0 * (bf2f((unsigned short)a0[j]) + bf2f((unsigned short)b0[j]))
             + w1 * (bf2f((unsigned short)a1[j]) + bf2f((unsigned short)b1[j]));
    float4* d = reinterpret_cast<float4*>(out + (size_t)i * 8);
    d[0] = make_float4(o[0], o[1], o[2], o[3]);
    d[1] = make_float4(o[4], o[5], o[6], o[7]);
}

// ================= fallback VALU path (proven baseline) =================
#define FB_BM 32
#define FB_BJ 128
#define FB_CK 256
#define FB_XSTR (FB_CK+4)
#define FB_HSTR (FB_BJ+4)

__device__ __forceinline__ float fb_gelu(float v) {
    return 0.5f * v * (1.0f + erff(v * 0.70710678118654752f));
}

__global__ void fb_init(int* cnt) { int i = threadIdx.x; if (i < NE) cnt[i] = 0; }

__global__ void fb_scatter(const int* __restrict__ eidx, int* cnt, int* bucket) {
    int a = blockIdx.x * 256 + threadIdx.x;
    if (a < NA) { int e = eidx[a]; int p = atomicAdd(&cnt[e], 1); bucket[e * NA + p] = a; }
}

__global__ __launch_bounds__(256, 1) void fb_fused(
    const float* __restrict__ x, const float* __restrict__ w1, const float* __restrict__ w2,
    const int* __restrict__ cnt, const int* __restrict__ bucket, float* __restrict__ ybuf)
{
    const int bid = blockIdx.x;
    const int e = bid & (NE - 1), tr = bid >> 3;
    const int n_e = cnt[e], rbase = tr * FB_BM;
    if (rbase >= n_e) return;
    const int t = threadIdx.x;
    __shared__ __align__(16) float Xc[FB_BM][FB_XSTR];
    __shared__ __align__(16) float Hsh[FB_BM][FB_HSTR];
    __shared__ int rowa[FB_BM];
    if (t < FB_BM) { int r = rbase + t; rowa[t] = (r < n_e) ? bucket[e * NA + r] : -1; }
    __syncthreads();
    const int cg = t & 15, rg = t >> 4, r0 = rg * 2;
    float yac[2][32];
    #pragma unroll
    for (int u = 0; u < 2; ++u)
        #pragma unroll
        for (int v = 0; v < 32; ++v) yac[u][v] = 0.0f;
    const float* w1e = w1 + (size_t)e * HS * FFN;
    const float* w2e = w2 + (size_t)e * FFN * HS;
    for (int jp = 0; jp < FFN; jp += FB_BJ) {
        float hac[2][8];
        #pragma unroll
        for (int u = 0; u < 2; ++u)
            #pragma unroll
            for (int v = 0; v < 8; ++v) hac[u][v] = 0.0f;
        for (int ic = 0; ic < HS; ic += FB_CK) {
            __syncthreads();
            #pragma unroll
            for (int q = 0; q < (FB_BM * FB_CK / 4) / 256; ++q) {
                int id = t + 256 * q, rr = id >> 6, c4 = id & 63;
                int a = rowa[rr];
                float4 val = make_float4(0.f, 0.f, 0.f, 0.f);
                if (a >= 0) val = *reinterpret_cast<const float4*>(x + (size_t)(a >> 1) * HS + ic + c4 * 4);
                *reinterpret_cast<float4*>(&Xc[rr][c4 * 4]) = val;
            }
            __syncthreads();
            const float* w1p = w1e + (size_t)ic * FFN + jp + cg * 8;
            #pragma unroll 2
            for (int i4 = 0; i4 < FB_CK; i4 += 4) {
                float4 xa = *reinterpret_cast<const float4*>(&Xc[r0][i4]);
                float4 xb = *reinterpret_cast<const float4*>(&Xc[r0 + 1][i4]);
                const float* wr0 = w1p + (size_t)i4 * FFN;
                #pragma unroll
                for (int ii = 0; ii < 4; ++ii) {
                    float4 wa = *reinterpret_cast<const float4*>(wr0 + (size_t)ii * FFN);
                    float4 wb = *reinterpret_cast<const float4*>(wr0 + (size_t)ii * FFN + 4);
                    float x0 = (ii == 0) ? xa.x : (ii == 1) ? xa.y : (ii == 2) ? xa.z : xa.w;
                    float x1 = (ii == 0) ? xb.x : (ii == 1) ? xb.y : (ii == 2) ? xb.z : xb.w;
                    hac[0][0] = fmaf(x0, wa.x, hac[0][0]); hac[0][1] = fmaf(x0, wa.y, hac[0][1]);
                    hac[0][2] = fmaf(x0, wa.z, hac[0][2]); hac[0][3] = fmaf(x0, wa.w, hac[0][3]);
                    hac[0][4] = fmaf(x0, wb.x, hac[0][4]); hac[0][5] = fmaf(x0, wb.y, hac[0][5]);
                    hac[0][6] = fmaf(x0, wb.z, hac[0][6]); hac[0][7] = fmaf(x0, wb.w, hac[0][7]);
                    hac[1][0] = fmaf(x1, wa.x, hac[1][0]); hac[1][1] = fmaf(x1, wa.y, hac[1][1]);
                    hac[1][2] = fmaf(x1, wa.z, hac[1][2]); hac[1][3] = fmaf(x1, wa.w, hac[1][3]);
                    hac[1][4] = fmaf(x1, wb.x, hac[1][4]); hac[1][5] = fmaf(x1, wb.y, hac[1][5]);
                    hac[1][6] = fmaf(x1, wb.z, hac[1][6]); hac[1][7] = fmaf(x1, wb.w, hac[1][7]);
                }
            }
        }
        #pragma unroll
        for (int u = 0; u < 2; ++u)
            #pragma unroll
            for (int v = 0; v < 8; ++v) Hsh[r0 + u][cg * 8 + v] = fb_gelu(hac[u][v]);
        __syncthreads();
        const float* w2p = w2e + (size_t)jp * HS + cg * 32;
        #pragma unroll 2
        for (int j = 0; j < FB_BJ; ++j) {
            float h0 = Hsh[r0][j], h1 = Hsh[r0 + 1][j];
            const float* wr = w2p + (size_t)j * HS;
            #pragma unroll
            for (int q = 0; q < 8; ++q) {
                float4 w4 = *reinterpret_cast<const float4*>(wr + q * 4);
                yac[0][q * 4 + 0] = fmaf(h0, w4.x, yac[0][q * 4 + 0]);
                yac[0][q * 4 + 1] = fmaf(h0, w4.y, yac[0][q * 4 + 1]);
                yac[0][q * 4 + 2] = fmaf(h0, w4.z, yac[0][q * 4 + 2]);
                yac[0][q * 4 + 3] = fmaf(h0, w4.w, yac[0][q * 4 + 3]);
                yac[1][q * 4 + 0] = fmaf(h1, w4.x, yac[1][q * 4 + 0]);
                yac[1][q * 4 + 1] = fmaf(h1, w4.y, yac[1][q * 4 + 1]);
                yac[1][q * 4 + 2] = fmaf(h1, w4.z, yac[1][q * 4 + 2]);
                yac[1][q * 4 + 3] = fmaf(h1, w4.w, yac[1][q * 4 + 3]);
            }
        }
    }
    #pragma unroll
    for (int u = 0; u < 2; ++u) {
        int a = rowa[r0 + u];
        if (a >= 0) {
            float* yp = ybuf + (size_t)a * HS + cg * 32;
            #pragma unroll
            for (int q = 0; q < 8; ++q) {
                float4 o = make_float4(yac[u][q * 4 + 0], yac[u][q * 4 + 1],
                                       yac[u][q * 4 + 2], yac[u][q * 4 + 3]);
                *reinterpret_cast<float4*>(yp + q * 4) = o;
            }
        }
    }
}

__global__ void fb_combine(const float* __restrict__ ybuf, const float* __restrict__ ew,
                           float* __restrict__ out) {
    int i = blockIdx.x * 256 + threadIdx.x;
    if (i >= T_TOK * HS / 4) return;
    int tk = i >> 7, c4 = i & 127;
    float wA = ew[2 * tk], wB = ew[2 * tk + 1];
    const float4* y4 = reinterpret_cast<const float4*>(ybuf);
    float4 a = y4[(size_t)(2 * tk) * (HS / 4) + c4];
    float4 b = y4[(size_t)(2 * tk + 1) * (HS / 4) + c4];
    float4 o;
    o.x = wA * a.x + wB * b.x; o.y = wA * a.y + wB * b.y;
    o.z = wA * a.z + wB * b.z; o.w = wA * a.w + wB * b.w;
    reinterpret_cast<float4*>(out)[i] = o;
}

// ================= launch =================
extern "C" void kernel_launch(void* const* d_in, const int* in_sizes, int n_in,
                              void* d_out, int out_size, void* d_ws, size_t ws_size,
                              hipStream_t stream) {
    const float* x  = (const float*)d_in[0];
    const float* ew = (const float*)d_in[1];
    const int*   ei = (const int*)d_in[2];
    const float* w1 = (const float*)d_in[3];
    const float* w2 = (const float*)d_in[4];
    float* out = (float*)d_out;
    char* W = (char*)d_ws;

    if (ws_size < WS_NEED) {
        int* cnt = (int*)d_ws;
        int* bucket = cnt + 64;
        float* ybuf = (float*)(W + (1 << 19));
        fb_init<<<1, 64, 0, stream>>>(cnt);
        fb_scatter<<<NA / 256, 256, 0, stream>>>(ei, cnt, bucket);
        fb_fused<<<NE * (NA / FB_BM), 256, 0, stream>>>(x, w1, w2, cnt, bucket, ybuf);
        fb_combine<<<(T_TOK * HS / 4 + 255) / 256, 256, 0, stream>>>(ybuf, ew, out);
        return;
    }

    int* offp  = (int*)(W + WS_OFF);
    int* mexp  = (int*)(W + WS_MEXP);
    int* slots = (int*)(W + WS_SLOTS);
    int* inv   = (int*)(W + WS_INV);
    unsigned short* XB   = (unsigned short*)(W + WS_XB);
    unsigned short* W1T  = (unsigned short*)(W + WS_W1T);
    unsigned short* W2T  = (unsigned short*)(W + WS_W2T);
    unsigned short* HB   = (unsigned short*)(W + WS_HB);
    unsigned short* YPB0 = (unsigned short*)(W + WS_YPB0);
    unsigned short* YPB1 = (unsigned short*)(W + WS_YPB1);

    moe_prep1<<<4129, 256, 0, stream>>>(ei, slots, inv, offp, mexp, x, XB, w1, W1T);
    moe_g1w2<<<NB_G1 + 2048, 256, 0, stream>>>(XB, W1T, offp, mexp, slots, HB, w2, W2T);
    moe_gemm2<<<8 * 9 * 8, 256, 0, stream>>>(HB, W2T, offp, mexp, YPB0, YPB1);
    moe_combine2<<<(T_TOK * HS / 8) / 256, 256, 0, stream>>>(YPB0, YPB1, inv, ew, out);
}

// Round 15
// 96.232 us; speedup vs baseline: 1.0578x; 1.0578x over previous
//
#include <hip/hip_runtime.h>
#include <stdint.h>

#define T_TOK 4096
#define KTOP  2
#define HS    512
#define FFN   2048
#define NE    8
#define NA    (T_TOK*KTOP)     // 8192 assignments
#define MT    128              // M-tile
#define BK    64               // K-step
#define MT_MAX 72              // 8 XCD chunks x 9
#define SLOT_CAP (MT_MAX*MT)   // 9216
#define PSTR 68                // epilogue LDS f32 stride
#define NB_G1 1152             // gemm1 blocks (128x128 tiles) in fused launch

// ---------------- workspace layout (bytes) ----------------
#define MB_ (1024ull*1024ull)
#define WS_OFF   1024u         // 9 ints
#define WS_MEXP  1088u         // 72 ints
#define WS_SLOTS 2048u         // 9216 ints
#define WS_INV   40960u        // 8192 ints
#define WS_XB   (1*MB_)        // 4MB  bf16 [4096][512]
#define WS_W1T  (5*MB_)        // 16MB bf16 [8][2048][512]
#define WS_W2T  (21*MB_)       // 16MB bf16 [8][512][2048]
#define WS_HB   (37*MB_)       // 36MB bf16 [9216][2048]
#define WS_YPB0 (73*MB_)       // 9MB bf16 [9216][512]
#define WS_YPB1 (82*MB_)       // 9MB
#define WS_NEED (91*MB_)

typedef short bf16x8 __attribute__((ext_vector_type(8)));
typedef float f32x4  __attribute__((ext_vector_type(4)));

__device__ __forceinline__ unsigned short f2bf(float f) {
    unsigned u = __builtin_bit_cast(unsigned, f);
    u += 0x7fffu + ((u >> 16) & 1u);          // RNE
    return (unsigned short)(u >> 16);
}
__device__ __forceinline__ float bf2f(unsigned short h) {
    return __builtin_bit_cast(float, (unsigned)h << 16);
}
// tanh-approx gelu (~10 VALU ops vs erff ~30; |err| <= ~3e-3; inf-safe both tails)
__device__ __forceinline__ float gelu_fast(float x) {
    float x2 = x * x;
    float inner = fmaf(0.044715f * x2, x, x);
    float E = __expf(1.5957691216057308f * inner);
    return x - x / (1.0f + E);
}
__device__ __forceinline__ void gl_lds16(const void* g, void* l) {
    __builtin_amdgcn_global_load_lds(
        (const __attribute__((address_space(1))) unsigned int*)g,
        (__attribute__((address_space(3))) unsigned int*)l, 16, 0, 0);
}

// 64x64 transpose+cvt tile: float4 global reads (1KB/inst), ushort4 writes.
__device__ __forceinline__ void transpose_cvt64(
    const float* __restrict__ src, unsigned short* __restrict__ dh,
    int R, int C, int e, int kb, int nb, int t, float (*tile)[65])
{
    const int k0 = kb * 64, n0 = nb * 64;
    #pragma unroll
    for (int q = 0; q < 4; ++q) {
        int f4 = t + q * 256;
        int kk = f4 >> 4, nn4 = f4 & 15;
        float4 v = *reinterpret_cast<const float4*>(
            &src[((size_t)e * R + k0 + kk) * C + n0 + nn4 * 4]);
        tile[kk][nn4 * 4 + 0] = v.x; tile[kk][nn4 * 4 + 1] = v.y;
        tile[kk][nn4 * 4 + 2] = v.z; tile[kk][nn4 * 4 + 3] = v.w;
    }
    __syncthreads();
    #pragma unroll
    for (int q = 0; q < 4; ++q) {
        int wid = t + q * 256;
        int nn = wid >> 4, kk4 = wid & 15;
        ushort4 o;
        o.x = f2bf(tile[kk4 * 4 + 0][nn]);
        o.y = f2bf(tile[kk4 * 4 + 1][nn]);
        o.z = f2bf(tile[kk4 * 4 + 2][nn]);
        o.w = f2bf(tile[kk4 * 4 + 3][nn]);
        *reinterpret_cast<ushort4*>(&dh[((size_t)e * C + n0 + nn) * R + k0 + kk4 * 4]) = o;
    }
}

// ---------------- prep1: cvt_x + w1T + deterministic routing ----------------
// ranges: [0,2048) x->bf16 | [2048,4096) w1T | [4096,4129) routing.
// Every range writes disjoint data consumed only by LATER kernels (R5 lesson).
// (w2T lives in the fused gemm1 launch -- only gemm2 needs it.)
__global__ void moe_prep1(const int* __restrict__ eidx,
                          int* slots, int* inv, int* offp, int* mexp,
                          const float* __restrict__ x, unsigned short* __restrict__ xb,
                          const float* __restrict__ w1, unsigned short* __restrict__ w1t)
{
    __shared__ float tile[64][65];
    const int bid = blockIdx.x, t = threadIdx.x;
    if (bid < 2048) {                         // x -> bf16
        int i = bid * 256 + t;
        float4 v = reinterpret_cast<const float4*>(x)[i];
        uint2 p = { (unsigned)f2bf(v.x) | ((unsigned)f2bf(v.y) << 16),
                    (unsigned)f2bf(v.z) | ((unsigned)f2bf(v.w) << 16) };
        reinterpret_cast<uint2*>(xb)[i] = p;
    } else if (bid < 4096) {                  // w1 [e][HS][FFN] -> [e][FFN][HS]
        int lin = bid - 2048, e = lin >> 8, rem = lin & 255;
        transpose_cvt64(w1, w1t, HS, FFN, e, rem & 7, rem >> 3, t, tile);
    } else {                                  // deterministic routing
        __shared__ int hfull[NE], hpre[NE], elocal[256];
        __shared__ int off_l[NE + 1];
        const int f = bid - 4096;             // 0..32
        if (t < NE) { hfull[t] = 0; hpre[t] = 0; }
        __syncthreads();
        const int base = f * 256;             // f==32 -> base==NA (no local slice)
        for (int i = t; i < NA; i += 256) {
            int ee = eidx[i];
            atomicAdd(&hfull[ee], 1);         // LDS atomics: cheap
            if (i < base) atomicAdd(&hpre[ee], 1);
        }
        if (f < 32) elocal[t] = eidx[base + t];
        __syncthreads();
        if (t == 0) {
            int run = 0;
            for (int q = 0; q < NE; ++q) { off_l[q] = run; run += ((hfull[q] + MT - 1) / MT) * MT; }
            off_l[NE] = run;
        }
        __syncthreads();
        if (f < 32) {
            int a = base + t, e = elocal[t];
            int rank = 0;
            for (int j = 0; j < t; ++j) rank += (elocal[j] == e) ? 1 : 0;
            int s = off_l[e] + hpre[e] + rank;
            slots[s] = a;                     // deterministic (stable order)
            inv[a] = s;
        } else {
            for (int e = 0; e < NE; ++e)
                for (int s = off_l[e] + hfull[e] + t; s < off_l[e + 1]; s += 256)
                    slots[s] = -1;            // pads (poison-safe each call)
            for (int s = off_l[NE] + t; s < SLOT_CAP; s += 256) slots[s] = -1;
            if (t <= NE) offp[t] = off_l[t];
            if (t < MT_MAX) {                 // mexp[t]: expert owning tile t
                int m0 = t * MT, ee = 0;
                #pragma unroll
                for (int q = 0; q < NE; ++q)
                    if (m0 >= off_l[q] && m0 < off_l[q + 1]) ee = q;
                mexp[t] = ee;
            }
        }
    }
}

// ---------------- fused: gemm1 128x128 (bid<1152) + w2T transpose (bid>=1152) ----------------
// gemm1: H = gelu(X @ W1), single-pass bf16, chunked XCD affinity.
// R14 lesson: 128x256 tile halved occupancy (4->2 blocks/CU) and LOST 10us --
// wave-level overlap across resident blocks beats barrier-count reduction.
// 128x128 + launch_bounds(256,4) is the verified optimum for this 2-barrier loop.
__global__ __launch_bounds__(256, 4) void moe_g1w2(
    const unsigned short* __restrict__ XB, const unsigned short* __restrict__ W1T,
    const int* __restrict__ offp, const int* __restrict__ mexp,
    const int* __restrict__ slots, unsigned short* __restrict__ HB,
    const float* __restrict__ w2, unsigned short* __restrict__ w2t)
{
    __shared__ __align__(16) char POOL[MT * PSTR * 4];
    __shared__ int srow[MT];
    const int t = threadIdx.x;

    if (blockIdx.x >= NB_G1) {                // ---- w2T path ----
        int lin = blockIdx.x - NB_G1;         // 0..2047
        int e = lin >> 8, rem = lin & 255;
        transpose_cvt64(w2, w2t, FFN, HS, e, rem & 31, rem >> 5, t,
                        reinterpret_cast<float(*)[65]>(POOL));
        return;
    }

    // ---- gemm1 path ----
    const int xcd = blockIdx.x & 7;
    const int part = blockIdx.x >> 3;     // 0..143
    const int mtg = part % 9;
    const int nt  = part / 9;             // 0..15
    const int mt  = xcd * 9 + mtg;
    if (mt * MT >= offp[NE]) return;
    const int e = mexp[mt];
    const int lane = t & 63, wv = t >> 6;

    short* As = (short*)POOL;                 // 16KB [128][64] bf16, 8-group XOR swz
    short* Bs = (short*)(POOL + 16384);       // 16KB
    float* Pf = (float*)POOL;                 // epilogue overlay

    if (t < MT) { int s = slots[mt * MT + t]; srow[t] = (s < 0) ? 0 : (s >> 1); }
    __syncthreads();

    int baseA[4], baseB[4];
    #pragma unroll
    for (int q = 0; q < 4; ++q) {
        int i = wv * 4 + q;
        int row = i * 8 + (lane >> 3);
        int sg = (lane & 7) ^ (row & 7);      // source swz [rule 21: both sides]
        baseA[q] = srow[row] * HS + sg * 8;
        baseB[q] = (e * FFN + nt * MT + row) * HS + sg * 8;
    }

    const int wm = wv >> 1, wn = wv & 1, q4 = lane >> 4, l15 = lane & 15;
    int offA[2][4], offB[2][4];
    #pragma unroll
    for (int m = 0; m < 4; ++m) {
        int r  = wm * 64 + m * 16 + l15;
        int rb = wn * 64 + m * 16 + l15;
        #pragma unroll
        for (int ks = 0; ks < 2; ++ks) {
            offA[ks][m] = r  * 128 + ((((ks << 2) | q4) ^ (r  & 7)) << 4);
            offB[ks][m] = rb * 128 + ((((ks << 2) | q4) ^ (rb & 7)) << 4);
        }
    }

    f32x4 acc[4][4];
    #pragma unroll
    for (int m = 0; m < 4; ++m)
        #pragma unroll
        for (int n = 0; n < 4; ++n) { f32x4 z = {0.f, 0.f, 0.f, 0.f}; acc[m][n] = z; }

    for (int kk = 0; kk < HS; kk += BK) {
        __syncthreads();
        #pragma unroll
        for (int q = 0; q < 4; ++q) {
            int i = wv * 4 + q;
            gl_lds16(XB  + baseA[q] + kk, (char*)As + i * 1024);
            gl_lds16(W1T + baseB[q] + kk, (char*)Bs + i * 1024);
        }
        __syncthreads();
        #pragma unroll
        for (int ks = 0; ks < 2; ++ks) {
            bf16x8 a[4], b[4];
            #pragma unroll
            for (int m = 0; m < 4; ++m) {
                a[m] = *(const bf16x8*)((const char*)As + offA[ks][m]);
                b[m] = *(const bf16x8*)((const char*)Bs + offB[ks][m]);
            }
            #pragma unroll
            for (int m = 0; m < 4; ++m)
                #pragma unroll
                for (int n = 0; n < 4; ++n)
                    acc[m][n] = __builtin_amdgcn_mfma_f32_16x16x32_bf16(a[m], b[n], acc[m][n], 0, 0, 0);
        }
    }

    // epilogue: LDS transpose -> coalesced bf16x8 stores (fast gelu in read phase)
    #pragma unroll
    for (int half = 0; half < 2; ++half) {
        __syncthreads();
        if (wn == half) {
            #pragma unroll
            for (int m = 0; m < 4; ++m)
                #pragma unroll
                for (int n = 0; n < 4; ++n)
                    #pragma unroll
                    for (int j = 0; j < 4; ++j)
                        Pf[(wm * 64 + m * 16 + q4 * 4 + j) * PSTR + n * 16 + l15] = acc[m][n][j];
        }
        __syncthreads();
        #pragma unroll
        for (int q = 0; q < 4; ++q) {
            int seg = q * 256 + t, row = seg >> 3, c8 = (seg & 7) << 3;
            const float* p = Pf + row * PSTR + c8;
            float4 a = *(const float4*)p, b = *(const float4*)(p + 4);
            float va[8] = {a.x, a.y, a.z, a.w, b.x, b.y, b.z, b.w};
            bf16x8 ph;
            #pragma unroll
            for (int i = 0; i < 8; ++i) ph[i] = (short)f2bf(gelu_fast(va[i]));
            *(bf16x8*)(HB + (size_t)(mt * MT + row) * FFN + nt * MT + half * 64 + c8) = ph;
        }
    }
}

// ---------------- grouped GEMM2: Y = H @ W2, split-K=2, bf16 partials ----------------
// Grid 576. sub-FAST decode: the 8 concurrent blocks on one XCD are all (nt,kpart)
// jobs of ONE mt -> A panel fetched once; B survives L2 across mtg rounds.
__global__ __launch_bounds__(256, 4) void moe_gemm2(
    const unsigned short* __restrict__ HB, const unsigned short* __restrict__ W2T,
    const int* __restrict__ offp, const int* __restrict__ mexp,
    unsigned short* __restrict__ YPB0, unsigned short* __restrict__ YPB1)
{
    const int xcd = blockIdx.x & 7;
    const int part = blockIdx.x >> 3;     // 0..71
    const int sub = part % 8;             // FAST: share one mt's A panel
    const int mtg = part / 8;             // 0..8
    const int mt  = xcd * 9 + mtg;
    const int nt  = sub >> 1, kpart = sub & 1;
    if (mt * MT >= offp[NE]) return;
    const int e = mexp[mt];
    const int t = threadIdx.x, lane = t & 63, wv = t >> 6;

    __shared__ __align__(16) char POOL[MT * PSTR * 4];
    short* As = (short*)POOL;
    short* Bs = (short*)(POOL + 16384);
    float* Pf = (float*)POOL;

    int baseA[4], baseB[4];
    #pragma unroll
    for (int q = 0; q < 4; ++q) {
        int i = wv * 4 + q;
        int row = i * 8 + (lane >> 3);
        int sg = (lane & 7) ^ (row & 7);
        baseA[q] = (mt * MT + row) * FFN + sg * 8;
        baseB[q] = (e * HS + nt * MT + row) * FFN + sg * 8;
    }

    const int wm = wv >> 1, wn = wv & 1, q4 = lane >> 4, l15 = lane & 15;
    int offA[2][4], offB[2][4];
    #pragma unroll
    for (int m = 0; m < 4; ++m) {
        int r  = wm * 64 + m * 16 + l15;
        int rb = wn * 64 + m * 16 + l15;
        #pragma unroll
        for (int ks = 0; ks < 2; ++ks) {
            offA[ks][m] = r  * 128 + ((((ks << 2) | q4) ^ (r  & 7)) << 4);
            offB[ks][m] = rb * 128 + ((((ks << 2) | q4) ^ (rb & 7)) << 4);
        }
    }

    f32x4 acc[4][4];
    #pragma unroll
    for (int m = 0; m < 4; ++m)
        #pragma unroll
        for (int n = 0; n < 4; ++n) { f32x4 z = {0.f, 0.f, 0.f, 0.f}; acc[m][n] = z; }

    const int k0 = kpart * (FFN / 2), k1 = k0 + FFN / 2;
    for (int kk = k0; kk < k1; kk += BK) {
        __syncthreads();
        #pragma unroll
        for (int q = 0; q < 4; ++q) {
            int i = wv * 4 + q;
            gl_lds16(HB  + baseA[q] + kk, (char*)As + i * 1024);
            gl_lds16(W2T + baseB[q] + kk, (char*)Bs + i * 1024);
        }
        __syncthreads();
        #pragma unroll
        for (int ks = 0; ks < 2; ++ks) {
            bf16x8 a[4], b[4];
            #pragma unroll
            for (int m = 0; m < 4; ++m) {
                a[m] = *(const bf16x8*)((const char*)As + offA[ks][m]);
                b[m] = *(const bf16x8*)((const char*)Bs + offB[ks][m]);
            }
            #pragma unroll
            for (int m = 0; m < 4; ++m)
                #pragma unroll
                for (int n = 0; n < 4; ++n)
                    acc[m][n] = __builtin_amdgcn_mfma_f32_16x16x32_bf16(a[m], b[n], acc[m][n], 0, 0, 0);
        }
    }

    unsigned short* YP = kpart ? YPB1 : YPB0;
    #pragma unroll
    for (int half = 0; half < 2; ++half) {
        __syncthreads();
        if (wn == half) {
            #pragma unroll
            for (int m = 0; m < 4; ++m)
                #pragma unroll
                for (int n = 0; n < 4; ++n)
                    #pragma unroll
                    for (int j = 0; j < 4; ++j)
                        Pf[(wm * 64 + m * 16 + q4 * 4 + j) * PSTR + n * 16 + l15] = acc[m][n][j];
        }
        __syncthreads();
        #pragma unroll
        for (int q = 0; q < 4; ++q) {
            int seg = q * 256 + t, row = seg >> 3, c8 = (seg & 7) << 3;
            const float* p = Pf + row * PSTR + c8;
            float4 a = *(const float4*)p, b = *(const float4*)(p + 4);
            float va[8] = {a.x, a.y, a.z, a.w, b.x, b.y, b.z, b.w};
            bf16x8 ph;
            #pragma unroll
            for (int i = 0; i < 8; ++i) ph[i] = (short)f2bf(va[i]);
            *(bf16x8*)(YP + (size_t)(mt * MT + row) * HS + nt * MT + half * 64 + c8) = ph;
        }
    }
}

// ---------------- combine (bf16 partials) ----------------
__global__ void moe_combine2(const unsigned short* __restrict__ YPB0,
                             const unsigned short* __restrict__ YPB1,
                             const int* __restrict__ inv, const float* __restrict__ ew,
                             float* __restrict__ out) {
    int i = blockIdx.x * 256 + threadIdx.x;      // over T*HS/8 groups of 8
    if (i >= T_TOK * HS / 8) return;
    int tk = i >> 6, c8 = (i & 63) << 3;
    int s0 = inv[2 * tk], s1 = inv[2 * tk + 1];
    float w0 = ew[2 * tk], w1 = ew[2 * tk + 1];
    bf16x8 a0 = *(const bf16x8*)(YPB0 + (size_t)s0 * HS + c8);
    bf16x8 b0 = *(const bf16x8*)(YPB1 + (size_t)s0 * HS + c8);
    bf16x8 a1 = *(const bf16x8*)(YPB0 + (size_t)s1 * HS + c8);
    bf16x8 b1 = *(const bf16x8*)(YPB1 + (size_t)s1 * HS + c8);
    float o[8];
    #pragma unroll
    for (int j = 0; j < 8; ++j)
        o[j] = w0 * (bf2f((unsigned short)a0[j]) + bf2f((unsigned short)b0[j]))
             + w1 * (bf2f((unsigned short)a1[j]) + bf2f((unsigned short)b1[j]));
    float4* d = reinterpret_cast<float4*>(out + (size_t)i * 8);
    d[0] = make_float4(o[0], o[1], o[2], o[3]);
    d[1] = make_float4(o[4], o[5], o[6], o[7]);
}

// ================= fallback VALU path (proven baseline) =================
#define FB_BM 32
#define FB_BJ 128
#define FB_CK 256
#define FB_XSTR (FB_CK+4)
#define FB_HSTR (FB_BJ+4)

__device__ __forceinline__ float fb_gelu(float v) {
    return 0.5f * v * (1.0f + erff(v * 0.70710678118654752f));
}

__global__ void fb_init(int* cnt) { int i = threadIdx.x; if (i < NE) cnt[i] = 0; }

__global__ void fb_scatter(const int* __restrict__ eidx, int* cnt, int* bucket) {
    int a = blockIdx.x * 256 + threadIdx.x;
    if (a < NA) { int e = eidx[a]; int p = atomicAdd(&cnt[e], 1); bucket[e * NA + p] = a; }
}

__global__ __launch_bounds__(256, 1) void fb_fused(
    const float* __restrict__ x, const float* __restrict__ w1, const float* __restrict__ w2,
    const int* __restrict__ cnt, const int* __restrict__ bucket, float* __restrict__ ybuf)
{
    const int bid = blockIdx.x;
    const int e = bid & (NE - 1), tr = bid >> 3;
    const int n_e = cnt[e], rbase = tr * FB_BM;
    if (rbase >= n_e) return;
    const int t = threadIdx.x;
    __shared__ __align__(16) float Xc[FB_BM][FB_XSTR];
    __shared__ __align__(16) float Hsh[FB_BM][FB_HSTR];
    __shared__ int rowa[FB_BM];
    if (t < FB_BM) { int r = rbase + t; rowa[t] = (r < n_e) ? bucket[e * NA + r] : -1; }
    __syncthreads();
    const int cg = t & 15, rg = t >> 4, r0 = rg * 2;
    float yac[2][32];
    #pragma unroll
    for (int u = 0; u < 2; ++u)
        #pragma unroll
        for (int v = 0; v < 32; ++v) yac[u][v] = 0.0f;
    const float* w1e = w1 + (size_t)e * HS * FFN;
    const float* w2e = w2 + (size_t)e * FFN * HS;
    for (int jp = 0; jp < FFN; jp += FB_BJ) {
        float hac[2][8];
        #pragma unroll
        for (int u = 0; u < 2; ++u)
            #pragma unroll
            for (int v = 0; v < 8; ++v) hac[u][v] = 0.0f;
        for (int ic = 0; ic < HS; ic += FB_CK) {
            __syncthreads();
            #pragma unroll
            for (int q = 0; q < (FB_BM * FB_CK / 4) / 256; ++q) {
                int id = t + 256 * q, rr = id >> 6, c4 = id & 63;
                int a = rowa[rr];
                float4 val = make_float4(0.f, 0.f, 0.f, 0.f);
                if (a >= 0) val = *reinterpret_cast<const float4*>(x + (size_t)(a >> 1) * HS + ic + c4 * 4);
                *reinterpret_cast<float4*>(&Xc[rr][c4 * 4]) = val;
            }
            __syncthreads();
            const float* w1p = w1e + (size_t)ic * FFN + jp + cg * 8;
            #pragma unroll 2
            for (int i4 = 0; i4 < FB_CK; i4 += 4) {
                float4 xa = *reinterpret_cast<const float4*>(&Xc[r0][i4]);
                float4 xb = *reinterpret_cast<const float4*>(&Xc[r0 + 1][i4]);
                const float* wr0 = w1p + (size_t)i4 * FFN;
                #pragma unroll
                for (int ii = 0; ii < 4; ++ii) {
                    float4 wa = *reinterpret_cast<const float4*>(wr0 + (size_t)ii * FFN);
                    float4 wb = *reinterpret_cast<const float4*>(wr0 + (size_t)ii * FFN + 4);
                    float x0 = (ii == 0) ? xa.x : (ii == 1) ? xa.y : (ii == 2) ? xa.z : xa.w;
                    float x1 = (ii == 0) ? xb.x : (ii == 1) ? xb.y : (ii == 2) ? xb.z : xb.w;
                    hac[0][0] = fmaf(x0, wa.x, hac[0][0]); hac[0][1] = fmaf(x0, wa.y, hac[0][1]);
                    hac[0][2] = fmaf(x0, wa.z, hac[0][2]); hac[0][3] = fmaf(x0, wa.w, hac[0][3]);
                    hac[0][4] = fmaf(x0, wb.x, hac[0][4]); hac[0][5] = fmaf(x0, wb.y, hac[0][5]);
                    hac[0][6] = fmaf(x0, wb.z, hac[0][6]); hac[0][7] = fmaf(x0, wb.w, hac[0][7]);
                    hac[1][0] = fmaf(x1, wa.x, hac[1][0]); hac[1][1] = fmaf(x1, wa.y, hac[1][1]);
                    hac[1][2] = fmaf(x1, wa.z, hac[1][2]); hac[1][3] = fmaf(x1, wa.w, hac[1][3]);
                    hac[1][4] = fmaf(x1, wb.x, hac[1][4]); hac[1][5] = fmaf(x1, wb.y, hac[1][5]);
                    hac[1][6] = fmaf(x1, wb.z, hac[1][6]); hac[1][7] = fmaf(x1, wb.w, hac[1][7]);
                }
            }
        }
        #pragma unroll
        for (int u = 0; u < 2; ++u)
            #pragma unroll
            for (int v = 0; v < 8; ++v) Hsh[r0 + u][cg * 8 + v] = fb_gelu(hac[u][v]);
        __syncthreads();
        const float* w2p = w2e + (size_t)jp * HS + cg * 32;
        #pragma unroll 2
        for (int j = 0; j < FB_BJ; ++j) {
            float h0 = Hsh[r0][j], h1 = Hsh[r0 + 1][j];
            const float* wr = w2p + (size_t)j * HS;
            #pragma unroll
            for (int q = 0; q < 8; ++q) {
                float4 w4 = *reinterpret_cast<const float4*>(wr + q * 4);
                yac[0][q * 4 + 0] = fmaf(h0, w4.x, yac[0][q * 4 + 0]);
                yac[0][q * 4 + 1] = fmaf(h0, w4.y, yac[0][q * 4 + 1]);
                yac[0][q * 4 + 2] = fmaf(h0, w4.z, yac[0][q * 4 + 2]);
                yac[0][q * 4 + 3] = fmaf(h0, w4.w, yac[0][q * 4 + 3]);
                yac[1][q * 4 + 0] = fmaf(h1, w4.x, yac[1][q * 4 + 0]);
                yac[1][q * 4 + 1] = fmaf(h1, w4.y, yac[1][q * 4 + 1]);
                yac[1][q * 4 + 2] = fmaf(h1, w4.z, yac[1][q * 4 + 2]);
                yac[1][q * 4 + 3] = fmaf(h1, w4.w, yac[1][q * 4 + 3]);
            }
        }
    }
    #pragma unroll
    for (int u = 0; u < 2; ++u) {
        int a = rowa[r0 + u];
        if (a >= 0) {
            float* yp = ybuf + (size_t)a * HS + cg * 32;
            #pragma unroll
            for (int q = 0; q < 8; ++q) {
                float4 o = make_float4(yac[u][q * 4 + 0], yac[u][q * 4 + 1],
                                       yac[u][q * 4 + 2], yac[u][q * 4 + 3]);
                *reinterpret_cast<float4*>(yp + q * 4) = o;
            }
        }
    }
}

__global__ void fb_combine(const float* __restrict__ ybuf, const float* __restrict__ ew,
                           float* __restrict__ out) {
    int i = blockIdx.x * 256 + threadIdx.x;
    if (i >= T_TOK * HS / 4) return;
    int tk = i >> 7, c4 = i & 127;
    float wA = ew[2 * tk], wB = ew[2 * tk + 1];
    const float4* y4 = reinterpret_cast<const float4*>(ybuf);
    float4 a = y4[(size_t)(2 * tk) * (HS / 4) + c4];
    float4 b = y4[(size_t)(2 * tk + 1) * (HS / 4) + c4];
    float4 o;
    o.x = wA * a.x + wB * b.x; o.y = wA * a.y + wB * b.y;
    o.z = wA * a.z + wB * b.z; o.w = wA * a.w + wB * b.w;
    reinterpret_cast<float4*>(out)[i] = o;
}

// ================= launch =================
extern "C" void kernel_launch(void* const* d_in, const int* in_sizes, int n_in,
                              void* d_out, int out_size, void* d_ws, size_t ws_size,
                              hipStream_t stream) {
    const float* x  = (const float*)d_in[0];
    const float* ew = (const float*)d_in[1];
    const int*   ei = (const int*)d_in[2];
    const float* w1 = (const float*)d_in[3];
    const float* w2 = (const float*)d_in[4];
    float* out = (float*)d_out;
    char* W = (char*)d_ws;

    if (ws_size < WS_NEED) {
        int* cnt = (int*)d_ws;
        int* bucket = cnt + 64;
        float* ybuf = (float*)(W + (1 << 19));
        fb_init<<<1, 64, 0, stream>>>(cnt);
        fb_scatter<<<NA / 256, 256, 0, stream>>>(ei, cnt, bucket);
        fb_fused<<<NE * (NA / FB_BM), 256, 0, stream>>>(x, w1, w2, cnt, bucket, ybuf);
        fb_combine<<<(T_TOK * HS / 4 + 255) / 256, 256, 0, stream>>>(ybuf, ew, out);
        return;
    }

    int* offp  = (int*)(W + WS_OFF);
    int* mexp  = (int*)(W + WS_MEXP);
    int* slots = (int*)(W + WS_SLOTS);
    int* inv   = (int*)(W + WS_INV);
    unsigned short* XB   = (unsigned short*)(W + WS_XB);
    unsigned short* W1T  = (unsigned short*)(W + WS_W1T);
    unsigned short* W2T  = (unsigned short*)(W + WS_W2T);
    unsigned short* HB   = (unsigned short*)(W + WS_HB);
    unsigned short* YPB0 = (unsigned short*)(W + WS_YPB0);
    unsigned short* YPB1 = (unsigned short*)(W + WS_YPB1);

    moe_prep1<<<4129, 256, 0, stream>>>(ei, slots, inv, offp, mexp, x, XB, w1, W1T);
    moe_g1w2<<<NB_G1 + 2048, 256, 0, stream>>>(XB, W1T, offp, mexp, slots, HB, w2, W2T);
    moe_gemm2<<<8 * 9 * 8, 256, 0, stream>>>(HB, W2T, offp, mexp, YPB0, YPB1);
    moe_combine2<<<(T_TOK * HS / 8) / 256, 256, 0, stream>>>(YPB0, YPB1, inv, ew, out);
}